// Round 19
// baseline (190.765 us; speedup 1.0000x reference)
//
#include <hip/hip_runtime.h>

#define NGRAPH 1000
#define P      100
#define EPG    1200
#define INF    16
#define HID    64
#define NOUT   5

#define ASTR   88    // unified row: cols 0..63 Y, 64..71 T1a, 72..79 T2, 80..87 T1b
#define T2OFF  72
#define SLOTA  64
#define SLOTB  80
#define NPAD   112   // 7 MFMA row-tiles x 16; rows 100..111 = pad/metadata

// r19 = r18 + degree-balanced gather:
//   nodes counting-sorted by degree (desc) -> order[]; wave w owns ranks
//   [25w,25w+25) (contiguous => similar degrees per wave). Lanes 0..49 =
//   mains (25 nodes x 2 col-halves) walk [kb, kb+Tw); lanes 50..63 = 14
//   helpers walk overflow [kb+Tw, ke) of the wave's top-7 nodes; partials
//   combined via in-wave __shfl (no LDS/atomics/barriers). Tw = wave's
//   8th-largest degree => no unhelped node exceeds Tw (correctness) and
//   wave iteration bound drops from global max-deg (~25) to ~Tw (~19).
//   Rationale: r15 showed gather cost ~ per-wave ITERATION count (masked
//   lanes still burn issue slots), not walk count.
//
// LDS: A 112*88*4 = 39,424 + csr_src(u8) 1,200 = 40,624 -> 4 blocks/CU.
// Pad-row metadata (floats 8800+): deg@0(100i) cur@100(100i) csr_off@200(101i)
// dinv@304(100f) psum/buckets@404(320f) order(u8)@724 Tw(4i)@750.
// Guarded row<P epilogue stores keep metadata alive; pad-row A-frag garbage
// only pollutes discarded D rows >=100 (r16..r18 verified).
//
// HARD RULES (r6..r18): acc arrays compile-time unrolled only; gather loop
// body simple fp32 (r11/r17); csr in LDS (r13); W tables pre-split (r18).

typedef short short8 __attribute__((ext_vector_type(8)));
typedef float f32x4  __attribute__((ext_vector_type(4)));

__device__ __forceinline__ void bsplit(float x, short& h, short& l) {
    unsigned u = __float_as_uint(x);
    h = (short)(u >> 16);
    float hf = __uint_as_float(u & 0xffff0000u);
    l = (short)(__float_as_uint(x - hf) >> 16);
}

// ---- W split/transpose pre-kernel (runs every launch; ~3 us) ----
__global__ __launch_bounds__(256) void wprep(
    const float* __restrict__ W1, const float* __restrict__ W2,
    const float* __restrict__ W3, short* __restrict__ wt)
{
    const int i0 = blockIdx.x * blockDim.x + threadIdx.x;
    const int stride = gridDim.x * blockDim.x;
    for (int e = i0; e < HID * 56; e += stride) {           // layer 1, RK=56
        int c = e / 56, r = e % 56;
        float v = (r < 48) ? W1[r * HID + c] : 0.f;
        short h, l; bsplit(v, h, l);
        wt[e]        = h;
        wt[3584 + e] = l;
    }
    for (int e = i0; e < HID * 200; e += stride) {          // layers 2+3, RK=200
        int c = e / 200, r = e % 200;
        float v2 = (r < 192) ? W2[r * HID + c] : 0.f;
        float v3 = (r < 192) ? W3[r * HID + c] : 0.f;
        short h, l;
        bsplit(v2, h, l); wt[7168 + e]  = h; wt[19968 + e] = l;
        bsplit(v3, h, l); wt[32768 + e] = h; wt[45568 + e] = l;
    }
}

// ---- balanced gather: X1-type.  D[nn][dslot..] = -dinv^2 * sum_e S-rows ----
__device__ __forceinline__ void prop_x1(
    float* __restrict__ A, int soff, int dslot,
    const unsigned char* __restrict__ csr_src,
    int nn, int kb, int ke, int q4, float dn, int lane)
{
    float ax = 0.f, ay = 0.f, az = 0.f, aw = 0.f;
    for (int k = kb; k < ke; k++) {
        int s = csr_src[k];
        const float4 x = *(const float4*)&A[s * ASTR + soff + q4];
        ax += x.x; ay += x.y; az += x.z; aw += x.w;
    }
    // helper lanes (50+l) -> main lanes (l<14)
    float p0 = __shfl(ax, (lane + 50) & 63);
    float p1 = __shfl(ay, (lane + 50) & 63);
    float p2 = __shfl(az, (lane + 50) & 63);
    float p3 = __shfl(aw, (lane + 50) & 63);
    if (lane < 14) { ax += p0; ay += p1; az += p2; aw += p3; }
    if (lane < 50) {
        float m = -dn * dn;
        float4 o; o.x = m * ax; o.y = m * ay; o.z = m * az; o.w = m * aw;
        *(float4*)&A[nn * ASTR + dslot + q4] = o;
    }
}

// ---- balanced fused dual gather: X2(cb)->T2 and, if pre, X1(cb+8)->t1n ----
__device__ __forceinline__ void prop_dual(
    float* __restrict__ A, int t1c, int t1n, int ycur, int ynext, bool pre,
    const unsigned char* __restrict__ csr_src,
    int nn, int kb, int ke, int q4, float dn, int lane)
{
    float4 a2 = make_float4(0.f, 0.f, 0.f, 0.f);
    float4 a1 = make_float4(0.f, 0.f, 0.f, 0.f);
    if (pre) {
        for (int k = kb; k < ke; k++) {
            int s = csr_src[k];
            const float* rp = &A[s * ASTR + q4];
            const float4 x2 = *(const float4*)&rp[t1c];
            const float4 x1 = *(const float4*)&rp[ynext];
            a2.x += x2.x; a2.y += x2.y; a2.z += x2.z; a2.w += x2.w;
            a1.x += x1.x; a1.y += x1.y; a1.z += x1.z; a1.w += x1.w;
        }
    } else {
        for (int k = kb; k < ke; k++) {
            int s = csr_src[k];
            const float4 x2 = *(const float4*)&A[s * ASTR + t1c + q4];
            a2.x += x2.x; a2.y += x2.y; a2.z += x2.z; a2.w += x2.w;
        }
    }
    {
        float p0 = __shfl(a2.x, (lane + 50) & 63);
        float p1 = __shfl(a2.y, (lane + 50) & 63);
        float p2 = __shfl(a2.z, (lane + 50) & 63);
        float p3 = __shfl(a2.w, (lane + 50) & 63);
        if (lane < 14) { a2.x += p0; a2.y += p1; a2.z += p2; a2.w += p3; }
    }
    if (pre) {
        float p0 = __shfl(a1.x, (lane + 50) & 63);
        float p1 = __shfl(a1.y, (lane + 50) & 63);
        float p2 = __shfl(a1.z, (lane + 50) & 63);
        float p3 = __shfl(a1.w, (lane + 50) & 63);
        if (lane < 14) { a1.x += p0; a1.y += p1; a1.z += p2; a1.w += p3; }
    }
    if (lane < 50) {
        float d2 = dn * dn;
        const float4 y0 = *(const float4*)&A[nn * ASTR + ycur + q4];
        float m2 = -2.f * d2;
        float4 o2;
        o2.x = m2 * a2.x - y0.x; o2.y = m2 * a2.y - y0.y;
        o2.z = m2 * a2.z - y0.z; o2.w = m2 * a2.w - y0.w;
        *(float4*)&A[nn * ASTR + T2OFF + q4] = o2;
        if (pre) {
            float m1 = -d2;
            float4 o1;
            o1.x = m1 * a1.x; o1.y = m1 * a1.y;
            o1.z = m1 * a1.z; o1.w = m1 * a1.w;
            *(float4*)&A[nn * ASTR + t1n + q4] = o1;
        }
    }
}

// ---- one ChebConv layer: balanced gather + MFMA matmul (r18 verbatim) ----
template <int F, int FINAL>
__device__ __forceinline__ void cheb_layer(
    float* __restrict__ A,
    const unsigned char* __restrict__ csr_src,
    const int* __restrict__ csr_off,
    const float* __restrict__ dinv,
    const unsigned char* __restrict__ order,
    const int* __restrict__ Tw,
    const short* __restrict__ whi, const short* __restrict__ wlo,
    const float* __restrict__ bias, int tid)
{
    const int RK   = 3 * F + 8;
    const int lane = tid & 63;
    const int wv   = tid >> 6;

    // gather mapping (per-thread constants for this layer)
    int slot, gq;
    if (lane < 50) { slot = lane >> 1;        gq = lane & 1; }
    else           { slot = (lane - 50) >> 1; gq = (lane - 50) & 1; }
    const int nn  = order[wv * 25 + slot];
    const int kb0 = csr_off[nn], ke0 = csr_off[nn + 1];
    const int tw  = Tw[wv];
    const int cap = (kb0 + tw < ke0) ? kb0 + tw : ke0;
    const int gkb = (lane < 50) ? kb0 : cap;
    const int gke = (lane < 50) ? cap : ke0;
    const int gq4 = gq * 4;
    const float gdn = dinv[nn];

    // matmul mapping (r18 verbatim)
    const int n16  = lane & 15;
    const int q    = lane >> 4;         // K-quad: 0=Y(cb) 1=T1 2=T2 3=zero-B
    const int ncol = (wv << 4) + n16;

    f32x4 acc[7];
#pragma unroll
    for (int t = 0; t < 7; t++) { acc[t][0]=0.f; acc[t][1]=0.f; acc[t][2]=0.f; acc[t][3]=0.f; }

    prop_x1(A, 0, SLOTA, csr_src, nn, gkb, gke, gq4, gdn, lane);
    __syncthreads();

    int t1c = SLOTA, t1n = SLOTB;
    for (int cb = 0; cb < F; cb += 8) {
        const bool pre = (cb + 8 < F);
        prop_dual(A, t1c, t1n, cb, cb + 8, pre, csr_src,
                  nn, gkb, gke, gq4, gdn, lane);
        __syncthreads();

        const int wr = (q == 0) ? cb : (q == 1) ? (F + cb)
                     : (q == 2) ? (2 * F + cb) : (3 * F);
        const short8 bhi = *(const short8*)&whi[ncol * RK + wr];
        const short8 blo = *(const short8*)&wlo[ncol * RK + wr];

        const int aoff = (q == 0) ? cb : (q == 1) ? t1c
                       : (q == 2) ? T2OFF : cb;
#pragma unroll
        for (int t = 0; t < 7; t++) {
            const float* xp = &A[(t * 16 + n16) * ASTR + aoff];
            const float4 v0 = *(const float4*)xp;
            const float4 v1 = *(const float4*)(xp + 4);
            short8 ahi, alo; short h, l;
            bsplit(v0.x, h, l); ahi[0] = h; alo[0] = l;
            bsplit(v0.y, h, l); ahi[1] = h; alo[1] = l;
            bsplit(v0.z, h, l); ahi[2] = h; alo[2] = l;
            bsplit(v0.w, h, l); ahi[3] = h; alo[3] = l;
            bsplit(v1.x, h, l); ahi[4] = h; alo[4] = l;
            bsplit(v1.y, h, l); ahi[5] = h; alo[5] = l;
            bsplit(v1.z, h, l); ahi[6] = h; alo[6] = l;
            bsplit(v1.w, h, l); ahi[7] = h; alo[7] = l;
            acc[t] = __builtin_amdgcn_mfma_f32_16x16x32_bf16(ahi, bhi, acc[t], 0, 0, 0);
            acc[t] = __builtin_amdgcn_mfma_f32_16x16x32_bf16(ahi, blo, acc[t], 0, 0, 0);
            acc[t] = __builtin_amdgcn_mfma_f32_16x16x32_bf16(alo, bhi, acc[t], 0, 0, 0);
        }
        __syncthreads();
        int tt = t1c; t1c = t1n; t1n = tt;
    }

    // Epilogue (r18 verbatim): D col=lane&15, row=(lane>>4)*4+reg.
    const float bcol = bias[ncol];
    const int rbase = q * 4;
#pragma unroll
    for (int t = 0; t < 7; t++) {
#pragma unroll
        for (int r = 0; r < 4; r++) {
            int row = t * 16 + rbase + r;
            if (row < P) {
                float dnr = dinv[row];
                float v = acc[t][r];
                float o;
                if (FINAL) o = fmaxf(v * (1.0f / dnr) + bcol, 0.f);
                else       o = fmaxf(v + bcol * dnr, 0.f);
                A[row * ASTR + ncol] = o;
            }
        }
    }
    __syncthreads();
}

__global__ __launch_bounds__(256, 4) void gnn_kernel(
    const float* __restrict__ feat,
    const int* __restrict__ src, const int* __restrict__ dst,
    const float* __restrict__ b1, const float* __restrict__ b2,
    const float* __restrict__ b3,
    const float* __restrict__ Wfc, const float* __restrict__ bfc,
    const short* __restrict__ wt,
    float* __restrict__ out)
{
    __shared__ __align__(16) float A[NPAD * ASTR];
    __shared__ unsigned char csr_src[EPG];

    const int g = blockIdx.x;
    const int tid = threadIdx.x;
    const int base = g * P;
    const int* srcg = src + g * EPG;
    const int* dstg = dst + g * EPG;

    int*   deg     = (int*)&A[P * ASTR];              // +0   (100 i32)
    int*   cur     = (int*)&A[P * ASTR + 100];        // +100 (100 i32)
    int*   csr_off = (int*)&A[P * ASTR + 200];        // +200 (101 i32)
    float* dinv    = &A[P * ASTR + 304];              // +304 (100 f32)
    float* psum    = &A[P * ASTR + 404];              // +404 (320 f32; sort buckets)
    unsigned char* order = (unsigned char*)&A[P * ASTR + 724];  // 100 u8
    int*   Tw      = (int*)&A[P * ASTR + 750];        // 4 i32

    // ---- degree count ----
    for (int i = tid; i < P; i += 256) deg[i] = 0;
    __syncthreads();
    for (int e = tid; e < EPG; e += 256) {
        int d = dstg[e] - base;
        atomicAdd(&deg[d], 1);
    }
    __syncthreads();

    // ---- dinv + serial prefix scan ----
    for (int i = tid; i < P; i += 256) {
        int dg = deg[i] > 1 ? deg[i] : 1;
        dinv[i] = rsqrtf((float)dg);
    }
    if (tid == 0) {
        int run = 0;
        csr_off[0] = 0;
        for (int i = 0; i < P; i++) { run += deg[i]; csr_off[i + 1] = run; }
    }
    __syncthreads();

    // ---- feat load prescaled + CSR cursor init ----
    for (int i = tid; i < P * INF / 4; i += 256) {
        int n = i >> 2, fq = (i & 3) * 4;
        float4 v = *(const float4*)&feat[(size_t)base * INF + i * 4];
        float dn = dinv[n];
        v.x *= dn; v.y *= dn; v.z *= dn; v.w *= dn;
        *(float4*)&A[n * ASTR + fq] = v;
    }
    for (int i = tid; i < P; i += 256) cur[i] = csr_off[i];
    __syncthreads();

    // ---- CSR fill (threads 0..254) || counting sort by degree (thread 255)
    if (tid < 255) {
        for (int e = tid; e < EPG; e += 255) {
            int s = srcg[e] - base;
            int d = dstg[e] - base;
            int pos = atomicAdd(&cur[d], 1);
            csr_src[pos] = (unsigned char)s;
        }
    } else {
        int* bucket = (int*)psum;                 // 64 ints
        for (int i = 0; i < 64; i++) bucket[i] = 0;
        for (int i = 0; i < P; i++) { int d = deg[i] < 63 ? deg[i] : 63; bucket[d]++; }
        int run = 0;
        for (int d = 63; d >= 0; d--) { int c = bucket[d]; bucket[d] = run; run += c; }
        for (int i = 0; i < P; i++) {
            int d = deg[i] < 63 ? deg[i] : 63;
            order[bucket[d]++] = (unsigned char)i;
        }
        for (int w = 0; w < 4; w++) Tw[w] = deg[order[w * 25 + 7]];
    }
    __syncthreads();

    // ---- 3 ChebConv layers ----
    cheb_layer<INF, 0>(A, csr_src, csr_off, dinv, order, Tw, wt,         wt + 3584,  b1, tid);
    cheb_layer<HID, 0>(A, csr_src, csr_off, dinv, order, Tw, wt + 7168,  wt + 19968, b2, tid);
    cheb_layer<HID, 1>(A, csr_src, csr_off, dinv, order, Tw, wt + 32768, wt + 45568, b3, tid);

    // ---- mean pool + FC ----
    {
        const int lane = tid & 63, w = tid >> 6;
        float s = 0.f;
        for (int n = w; n < P; n += 4) s += A[n * ASTR + lane];
        psum[w * 64 + lane] = s;
    }
    __syncthreads();
    if (tid < HID) {
        float hg = (psum[tid] + psum[64 + tid] + psum[128 + tid] + psum[192 + tid]) * (1.0f / P);
        psum[256 + tid] = hg;
    }
    __syncthreads();
    if (tid < NOUT) {
        float o = bfc[tid];
        for (int c = 0; c < HID; c++) o += psum[256 + c] * Wfc[c * NOUT + tid];
        out[g * NOUT + tid] = o;
    }
}

extern "C" void kernel_launch(void* const* d_in, const int* in_sizes, int n_in,
                              void* d_out, int out_size, void* d_ws, size_t ws_size,
                              hipStream_t stream)
{
    const float* feat = (const float*)d_in[0];
    const int*   src  = (const int*)d_in[1];
    const int*   dst  = (const int*)d_in[2];
    const float* W1  = (const float*)d_in[5];
    const float* b1  = (const float*)d_in[6];
    const float* W2  = (const float*)d_in[7];
    const float* b2  = (const float*)d_in[8];
    const float* W3  = (const float*)d_in[9];
    const float* b3  = (const float*)d_in[10];
    const float* Wfc = (const float*)d_in[11];
    const float* bfc = (const float*)d_in[12];
    float* out = (float*)d_out;
    short* wt = (short*)d_ws;

    wprep<<<64, 256, 0, stream>>>(W1, W2, W3, wt);
    gnn_kernel<<<NGRAPH, 256, 0, stream>>>(feat, src, dst,
                                           b1, b2, b3, Wfc, bfc, wt, out);
}